// Round 16
// baseline (729.066 us; speedup 1.0000x reference)
//
#include <hip/hip_runtime.h>
#include <hip/hip_bf16.h>

#define HW 65536
#define SCALE_Q 0.17677669529663687f

typedef __bf16 bf16x8 __attribute__((ext_vector_type(8)));
typedef float f32x4 __attribute__((ext_vector_type(4)));

// ---------------- K0: rel-pos MLP bias in C-fragment layout ----------------
__global__ void bias_kernel(const float* __restrict__ w1, const float* __restrict__ b1,
                            const float* __restrict__ w2, const float* __restrict__ b2,
                            float* __restrict__ biasF) {
    int gid = blockIdx.x * blockDim.x + threadIdx.x;
    if (gid >= 12288) return;
    int lane = gid & 63, r = (gid >> 6) & 3, ni = (gid >> 8) & 3, mi = (gid >> 10) & 3, h = gid >> 12;
    int i = mi * 16 + ((lane >> 4) << 2) + r;
    int j = ni * 16 + (lane & 15);
    float di = (float)((i >> 3) - (j >> 3));
    float dj = (float)((i & 7) - (j & 7));
    float r0 = (di > 0.f ? 1.f : (di < 0.f ? -1.f : 0.f)) * log1pf(fabsf(di));
    float r1 = (dj > 0.f ? 1.f : (dj < 0.f ? -1.f : 0.f)) * log1pf(fabsf(dj));
    float acc = 0.f;
    for (int t = 0; t < 256; ++t) {
        float u = fmaf(w1[2 * t], r0, fmaf(w1[2 * t + 1], r1, b1[t]));
        u = fmaxf(u, 0.f);
        acc = fmaf(w2[h * 256 + t], u, acc);
    }
    biasF[gid] = acc + b2[h];
}

// ---------------- K0b: weight prep (bf16 hi/lo: QKV rows + proj rows) ----------
__global__ void wtrans_kernel(const float* __restrict__ QK_w, const float* __restrict__ V_w,
                              const float* __restrict__ proj_w,
                              __bf16* __restrict__ Whi, __bf16* __restrict__ Wlo,
                              __bf16* __restrict__ WpHi, __bf16* __restrict__ WpLo) {
    int idx = blockIdx.x * blockDim.x + threadIdx.x;
    if (idx < 288 * 96) {
        int oo = idx / 96, c = idx - oo * 96;
        int h = oo / 96, rem = oo - h * 96, grp = rem >> 5, d = rem & 31;
        float w = (grp == 0) ? QK_w[(h * 32 + d) * 96 + c]
                : (grp == 1) ? QK_w[(96 + h * 32 + d) * 96 + c]
                             : V_w[(h * 32 + d) * 96 + c];
        __bf16 hi = (__bf16)w;
        Whi[idx] = hi;
        Wlo[idx] = (__bf16)(w - (float)hi);
    } else if (idx < 288 * 96 + 96 * 96) {
        int rdx = idx - 288 * 96;
        float w = proj_w[rdx];
        __bf16 hi = (__bf16)w;
        WpHi[rdx] = hi;
        WpLo[rdx] = (__bf16)(w - (float)hi);
    }
}

// ---------------- K0c: x -> xT[win][ks][g][tok][8ch] bf16 (A-fragment-ready) ----------
__global__ __launch_bounds__(256) void xprep_kernel(const float* __restrict__ x,
                                                    __bf16* __restrict__ xT) {
    __shared__ __bf16 Xs[26624];   // [4 win][64 tok][104]
    int tid = threadIdx.x;
    int bxs = blockIdx.x;
    int b = bxs >> 8;
    int wh = (bxs >> 3) & 31;
    int ww0 = (bxs & 7) << 2;
    int wh8 = wh << 3, wb8 = ww0 << 3;
    const float* xb = x + (size_t)b * 96 * HW;
    for (int idx = tid; idx < 24576; idx += 256) {
        int c = idx >> 8, r = (idx >> 5) & 7, col = idx & 31;
        int pph = (wh8 + r + 4) & 255;
        int ppw = (wb8 + col + 4) & 255;
        Xs[(col >> 3) * 6656 + (r * 8 + (col & 7)) * 104 + c] =
            (__bf16)xb[(size_t)c * HW + pph * 256 + ppw];
    }
    __syncthreads();
    int win = tid >> 6, t = tid & 63;
    const __bf16* row = Xs + win * 6656 + t * 104;
    __bf16* dst = xT + (size_t)(b * 1024 + wh * 32 + ww0 + win) * 6144 + t * 8;
#pragma unroll
    for (int ks = 0; ks < 3; ++ks)
#pragma unroll
        for (int g = 0; g < 4; ++g)
            *(bf16x8*)(dst + (ks * 4 + g) * 512) = *(const bf16x8*)(row + ks * 32 + g * 8);
}

// ---------------- K1: fused QKV conv + window attention ----------------
// MODE 2: A from xT (16B loads), xr window-tiled bf16 (wave-owned 128B lines).
// MODE 1: A direct from x, xr planar bf16.  MODE 0: A direct, xr f32 (d_out).
template <int MODE>
__global__ __launch_bounds__(256, 4) void fused_qkv_attn(
    const float* __restrict__ x, const __bf16* __restrict__ xT,
    const __bf16* __restrict__ Whi, const __bf16* __restrict__ Wlo,
    const float* __restrict__ QK_b, const float* __restrict__ V_b,
    const float* __restrict__ biasF,
    unsigned short* __restrict__ Vout, void* __restrict__ xrv) {
    __shared__ __align__(16) char lds[39936];
    int tid = threadIdx.x;
    int w4 = tid >> 6;
    int lane = tid & 63;
    int l16 = lane & 15;
    int g8 = (lane >> 4) << 3;
    int g4 = (lane >> 4) << 2;
    int bx0 = blockIdx.x;
    int bxs = (bx0 & 7) * 256 + (bx0 >> 3);
    int b = bxs >> 8;
    int wh = (bxs >> 3) & 31;
    int ww0 = (bxs & 7) << 2;
    int wh8 = wh << 3;
    int ww = ww0 + w4;
    int wl = wh * 32 + ww;
    int ti = lane >> 3, tj = lane & 7;
    int ph = (wh8 + ti + 4) & 255;
    int pw = ((ww << 3) + tj + 4) & 255;
    int pos   = ph * 256 + pw;
    int pos_s = (wh8 + ti) * 256 + (ww << 3) + tj;

    bf16x8 Ah[4][3];
    if constexpr (MODE == 2) {
        const __bf16* xTw = xT + (size_t)(b * 1024 + wl) * 6144;
#pragma unroll
        for (int mi = 0; mi < 4; ++mi)
#pragma unroll
            for (int ks = 0; ks < 3; ++ks)
                Ah[mi][ks] = *(const bf16x8*)(xTw + (ks * 4 + (lane >> 4)) * 512 + (mi * 16 + l16) * 8);
    } else {
        const float* xb = x + (size_t)b * 96 * HW;
#pragma unroll
        for (int mi = 0; mi < 4; ++mi) {
            int t = mi * 16 + l16;
            int py = (wh8 + (t >> 3) + 4) & 255;
            int px = ((ww << 3) + (t & 7) + 4) & 255;
            const float* xp = xb + py * 256 + px + (size_t)g8 * HW;
#pragma unroll
            for (int ks = 0; ks < 3; ++ks)
#pragma unroll
                for (int e = 0; e < 8; ++e)
                    Ah[mi][ks][e] = (__bf16)xp[(size_t)(ks * 32 + e) * HW];
        }
    }

    char* hb = lds + w4 * 9984;
    __bf16* slab = (__bf16*)hb;            // [64][40] bf16: Q, K, P stages; Xrt overlay
    __bf16* Vt   = (__bf16*)(hb + 5120);   // [32 d][72 tok]
    float*  Xr   = (float*)hb;             // [64][36] f32 overlay (MODE<2 epilogue)

    bool bhh = (wh == 31), bww = (ww == 31);
    int rc[4];
#pragma unroll
    for (int ni = 0; ni < 4; ++ni) {
        int t = ni * 16 + l16;
        rc[ni] = (bhh ? (((t >> 3) < 4) ? 1 : 2) : 0) * 3 + (bww ? (((t & 7) < 4) ? 1 : 2) : 0);
    }

#pragma unroll 1
    for (int h = 0; h < 3; ++h) {
        bf16x8 Qf[4], Kf[4];
        // ---- Q (1-pass) ----
        {
            f32x4 acc[4][2];
#pragma unroll
            for (int mi = 0; mi < 4; ++mi)
#pragma unroll
                for (int ni = 0; ni < 2; ++ni) acc[mi][ni] = (f32x4){0.f, 0.f, 0.f, 0.f};
            __builtin_amdgcn_s_setprio(1);
#pragma unroll
            for (int ks = 0; ks < 3; ++ks)
#pragma unroll
                for (int ni = 0; ni < 2; ++ni) {
                    bf16x8 Bh = *(const bf16x8*)(Whi + (h * 96 + ni * 16 + l16) * 96 + ks * 32 + g8);
#pragma unroll
                    for (int mi = 0; mi < 4; ++mi)
                        acc[mi][ni] = __builtin_amdgcn_mfma_f32_16x16x32_bf16(Ah[mi][ks], Bh, acc[mi][ni], 0, 0, 0);
                }
            __builtin_amdgcn_s_setprio(0);
#pragma unroll
            for (int ni = 0; ni < 2; ++ni) {
                float bias = QK_b[h * 32 + ni * 16 + l16];
#pragma unroll
                for (int mi = 0; mi < 4; ++mi)
#pragma unroll
                    for (int r = 0; r < 4; ++r)
                        slab[(mi * 16 + g4 + r) * 40 + ni * 16 + l16] = (__bf16)((acc[mi][ni][r] + bias) * SCALE_Q);
            }
#pragma unroll
            for (int mi = 0; mi < 4; ++mi) Qf[mi] = *(const bf16x8*)(slab + (mi * 16 + l16) * 40 + g8);
        }
        // ---- K (1-pass) ----
        {
            f32x4 acc[4][2];
#pragma unroll
            for (int mi = 0; mi < 4; ++mi)
#pragma unroll
                for (int ni = 0; ni < 2; ++ni) acc[mi][ni] = (f32x4){0.f, 0.f, 0.f, 0.f};
            __builtin_amdgcn_s_setprio(1);
#pragma unroll
            for (int ks = 0; ks < 3; ++ks)
#pragma unroll
                for (int ni = 0; ni < 2; ++ni) {
                    bf16x8 Bh = *(const bf16x8*)(Whi + (h * 96 + 32 + ni * 16 + l16) * 96 + ks * 32 + g8);
#pragma unroll
                    for (int mi = 0; mi < 4; ++mi)
                        acc[mi][ni] = __builtin_amdgcn_mfma_f32_16x16x32_bf16(Ah[mi][ks], Bh, acc[mi][ni], 0, 0, 0);
                }
            __builtin_amdgcn_s_setprio(0);
#pragma unroll
            for (int ni = 0; ni < 2; ++ni) {
                float bias = QK_b[96 + h * 32 + ni * 16 + l16];
#pragma unroll
                for (int mi = 0; mi < 4; ++mi)
#pragma unroll
                    for (int r = 0; r < 4; ++r)
                        slab[(mi * 16 + g4 + r) * 40 + ni * 16 + l16] = (__bf16)(acc[mi][ni][r] + bias);
            }
#pragma unroll
            for (int mi = 0; mi < 4; ++mi) Kf[mi] = *(const bf16x8*)(slab + (mi * 16 + l16) * 40 + g8);
        }
        // ---- V (1-pass) ----
        {
            f32x4 acc[4][2];
#pragma unroll
            for (int mi = 0; mi < 4; ++mi)
#pragma unroll
                for (int ni = 0; ni < 2; ++ni) acc[mi][ni] = (f32x4){0.f, 0.f, 0.f, 0.f};
            __builtin_amdgcn_s_setprio(1);
#pragma unroll
            for (int ks = 0; ks < 3; ++ks)
#pragma unroll
                for (int ni = 0; ni < 2; ++ni) {
                    bf16x8 Bh = *(const bf16x8*)(Whi + (h * 96 + 64 + ni * 16 + l16) * 96 + ks * 32 + g8);
#pragma unroll
                    for (int mi = 0; mi < 4; ++mi)
                        acc[mi][ni] = __builtin_amdgcn_mfma_f32_16x16x32_bf16(Ah[mi][ks], Bh, acc[mi][ni], 0, 0, 0);
                }
            __builtin_amdgcn_s_setprio(0);
#pragma unroll
            for (int ni = 0; ni < 2; ++ni) {
                float bias = V_b[h * 32 + ni * 16 + l16];
#pragma unroll
                for (int mi = 0; mi < 4; ++mi)
#pragma unroll
                    for (int r = 0; r < 4; ++r)
                        Vt[(ni * 16 + l16) * 72 + mi * 16 + g4 + r] = (__bf16)(acc[mi][ni][r] + bias);
            }
        }
#pragma unroll
        for (int d = 0; d < 32; ++d)
            Vout[(size_t)(b * 96 + h * 32 + d) * HW + pos_s] = ((const unsigned short*)Vt)[d * 72 + lane];

        // ---- QK^T ----
        f32x4 sc[4][4];
        __builtin_amdgcn_s_setprio(1);
#pragma unroll
        for (int mi = 0; mi < 4; ++mi)
#pragma unroll
            for (int ni = 0; ni < 4; ++ni) {
                sc[mi][ni] = (f32x4){0.f, 0.f, 0.f, 0.f};
                sc[mi][ni] = __builtin_amdgcn_mfma_f32_16x16x32_bf16(Qf[mi], Kf[ni], sc[mi][ni], 0, 0, 0);
            }
        __builtin_amdgcn_s_setprio(0);
        const float* bF = biasF + h * 4096;
#pragma unroll
        for (int mi = 0; mi < 4; ++mi)
#pragma unroll
            for (int r = 0; r < 4; ++r) {
                int row = mi * 16 + g4 + r;
                float s0 = sc[mi][0][r] + bF[((mi * 4 + 0) * 4 + r) * 64 + lane];
                float s1 = sc[mi][1][r] + bF[((mi * 4 + 1) * 4 + r) * 64 + lane];
                float s2 = sc[mi][2][r] + bF[((mi * 4 + 2) * 4 + r) * 64 + lane];
                float s3 = sc[mi][3][r] + bF[((mi * 4 + 3) * 4 + r) * 64 + lane];
                if (bhh || bww) {
                    int rr = (bhh ? (((row >> 3) < 4) ? 1 : 2) : 0) * 3 +
                             (bww ? (((row & 7) < 4) ? 1 : 2) : 0);
                    if (rr != rc[0]) s0 -= 100.f;
                    if (rr != rc[1]) s1 -= 100.f;
                    if (rr != rc[2]) s2 -= 100.f;
                    if (rr != rc[3]) s3 -= 100.f;
                }
                float mm = fmaxf(fmaxf(s0, s1), fmaxf(s2, s3));
                mm = fmaxf(mm, __shfl_xor(mm, 1));
                mm = fmaxf(mm, __shfl_xor(mm, 2));
                mm = fmaxf(mm, __shfl_xor(mm, 4));
                mm = fmaxf(mm, __shfl_xor(mm, 8));
                float e0 = __expf(s0 - mm), e1 = __expf(s1 - mm);
                float e2 = __expf(s2 - mm), e3 = __expf(s3 - mm);
                float sum = e0 + e1 + e2 + e3;
                sum += __shfl_xor(sum, 1);
                sum += __shfl_xor(sum, 2);
                sum += __shfl_xor(sum, 4);
                sum += __shfl_xor(sum, 8);
                float inv = 1.f / sum;
                sc[mi][0][r] = e0 * inv;
                sc[mi][1][r] = e1 * inv;
                sc[mi][2][r] = e2 * inv;
                sc[mi][3][r] = e3 * inv;
            }
        // ---- PV (P staged through slab) ----
        f32x4 po[4][2];
#pragma unroll
        for (int mi = 0; mi < 4; ++mi)
#pragma unroll
            for (int ni = 0; ni < 2; ++ni) po[mi][ni] = (f32x4){0.f, 0.f, 0.f, 0.f};
#pragma unroll
        for (int ks = 0; ks < 2; ++ks) {
#pragma unroll
            for (int mi = 0; mi < 4; ++mi)
#pragma unroll
                for (int r = 0; r < 4; ++r) {
                    int row = mi * 16 + g4 + r;
                    slab[row * 40 + l16]      = (__bf16)sc[mi][ks * 2 + 0][r];
                    slab[row * 40 + 16 + l16] = (__bf16)sc[mi][ks * 2 + 1][r];
                }
            bf16x8 Vf[2], Pf;
#pragma unroll
            for (int ni = 0; ni < 2; ++ni)
                Vf[ni] = *(const bf16x8*)(Vt + (ni * 16 + l16) * 72 + ks * 32 + g8);
            __builtin_amdgcn_s_setprio(1);
#pragma unroll
            for (int mi = 0; mi < 4; ++mi) {
                Pf = *(const bf16x8*)(slab + (mi * 16 + l16) * 40 + g8);
#pragma unroll
                for (int ni = 0; ni < 2; ++ni)
                    po[mi][ni] = __builtin_amdgcn_mfma_f32_16x16x32_bf16(Pf, Vf[ni], po[mi][ni], 0, 0, 0);
            }
            __builtin_amdgcn_s_setprio(0);
        }
        // ---- xr epilogue ----
        if constexpr (MODE == 2) {
            // within-wave transpose to Xrt [32 d][stride 72] bf16, then wave-owned 128B lines
            __bf16* Xrt = slab;
#pragma unroll
            for (int mi = 0; mi < 4; ++mi)
#pragma unroll
                for (int ni = 0; ni < 2; ++ni)
#pragma unroll
                    for (int r = 0; r < 4; ++r)
                        Xrt[(ni * 16 + l16) * 72 + mi * 16 + g4 + r] = (__bf16)po[mi][ni][r];
            int d = lane >> 1, half = lane & 1;
            const unsigned short* src = (const unsigned short*)Xrt + d * 72 + half * 32;
            unsigned short* dst = (unsigned short*)xrv +
                ((size_t)(b * 96 + h * 32 + d) * 1024 + wl) * 64 + half * 32;
#pragma unroll
            for (int i = 0; i < 4; ++i)
                *(uint4*)(dst + i * 8) = *(const uint4*)(src + i * 8);
        } else {
#pragma unroll
            for (int mi = 0; mi < 4; ++mi)
#pragma unroll
                for (int ni = 0; ni < 2; ++ni)
#pragma unroll
                    for (int r = 0; r < 4; ++r)
                        Xr[(mi * 16 + g4 + r) * 36 + ni * 16 + l16] = po[mi][ni][r];
            if constexpr (MODE == 1) {
                unsigned short* xrg = (unsigned short*)xrv + (size_t)(b * 96 + h * 32) * HW + pos;
#pragma unroll
                for (int c4 = 0; c4 < 8; ++c4) {
                    f32x4 v = *(const f32x4*)(Xr + lane * 36 + c4 * 4);
#pragma unroll
                    for (int j = 0; j < 4; ++j) {
                        __bf16 t = (__bf16)v[j];
                        xrg[(size_t)(c4 * 4 + j) * HW] = *(unsigned short*)&t;
                    }
                }
            } else {
                float* xrg = (float*)xrv + (size_t)(b * 96 + h * 32) * HW + pos;
#pragma unroll
                for (int c4 = 0; c4 < 8; ++c4) {
                    f32x4 v = *(const f32x4*)(Xr + lane * 36 + c4 * 4);
                    xrg[(size_t)(c4 * 4 + 0) * HW] = v[0];
                    xrg[(size_t)(c4 * 4 + 1) * HW] = v[1];
                    xrg[(size_t)(c4 * 4 + 2) * HW] = v[2];
                    xrg[(size_t)(c4 * 4 + 3) * HW] = v[3];
                }
            }
        }
    }
}

// ---------------- K2: dwconv + xr -> bf16 LDS (128 px tile), 2-pass MFMA proj ----
template <int MODE>
__global__ __launch_bounds__(512) void dwproj_kernel(
    const __hip_bfloat16* __restrict__ Vs, const float* __restrict__ dw_w,
    const float* __restrict__ dw_b, const __bf16* __restrict__ WpHi,
    const __bf16* __restrict__ WpLo, const float* __restrict__ pb,
    const void* __restrict__ xrv, float* __restrict__ T) {
    __shared__ __align__(16) __bf16 Ts[13312];   // [128 px][104] bf16 = 26.6 KB
    int bx0 = blockIdx.x;
    int bx = (bx0 & 7) * 512 + (bx0 >> 3);   // XCD-contiguous rows (4096 % 8 == 0)
    int half = bx & 1, h = (bx >> 1) & 255, b = bx >> 9;
    int w0 = half << 7;
    int tid = threadIdx.x;
    for (int task = tid; task < 1536; task += 512) {
        int c = task >> 4, g = task & 15;
        int wbase = w0 + (g << 3);
        const __hip_bfloat16* Vp = Vs + (size_t)(b * 96 + c) * HW;
        const float* wt = dw_w + c * 25;
        float acc[8];
        float bias = dw_b[c];
#pragma unroll
        for (int i = 0; i < 8; ++i) acc[i] = bias;
        bool fast = (wbase >= 8) && (wbase <= 240);
#pragma unroll
        for (int dy = -2; dy <= 2; ++dy) {
            int hh = h + dy;
            hh = hh < 0 ? -hh : (hh > 255 ? 510 - hh : hh);
            int hs = (hh + 252) & 255;
            const __hip_bfloat16* row = Vp + hs * 256;
            float xv[12];
            if (fast) {
                const uint* rp = (const uint*)(row + (wbase - 6));
#pragma unroll
                for (int g2 = 0; g2 < 6; ++g2) {
                    uint u = rp[g2];
                    xv[2 * g2]     = __uint_as_float(u << 16);
                    xv[2 * g2 + 1] = __uint_as_float(u & 0xffff0000u);
                }
            } else {
#pragma unroll
                for (int idx = 0; idx < 12; ++idx) {
                    int cw = wbase - 2 + idx;
                    cw = cw < 0 ? -cw : (cw > 255 ? 510 - cw : cw);
                    int cs = (cw + 252) & 255;
                    uint u = *(const unsigned short*)(row + cs);
                    xv[idx] = __uint_as_float(u << 16);
                }
            }
            const float* w5 = wt + (dy + 2) * 5;
#pragma unroll
            for (int dx = 0; dx < 5; ++dx) {
                float wv = w5[dx];
#pragma unroll
                for (int i = 0; i < 8; ++i) acc[i] = fmaf(wv, xv[i + dx], acc[i]);
            }
        }
        if constexpr (MODE == 2) {
            // xr window-tiled in SHIFTED space. Original cols [wbase,wbase+8) map to
            // shifted cols [wbase-4,wbase+4): tokens 4..7 of window (ps2>>3), then
            // tokens 0..3 of window (wbase>>3). Row hs2 = (h-4)&255 (no straddle).
            int hs2 = (h + 252) & 255;
            int ps2 = (wbase + 252) & 255;
            int wrow = (hs2 >> 3) * 32;
            int rowoff = (hs2 & 7) * 8;
            const unsigned short* base = (const unsigned short*)xrv + (size_t)(b * 96 + c) * HW;
            uint2 A = *(const uint2*)(base + (size_t)(wrow + (ps2 >> 3)) * 64 + rowoff + 4);
            uint2 B = *(const uint2*)(base + (size_t)(wrow + (wbase >> 3)) * 64 + rowoff);
            acc[0] += __uint_as_float(A.x << 16);
            acc[1] += __uint_as_float(A.x & 0xffff0000u);
            acc[2] += __uint_as_float(A.y << 16);
            acc[3] += __uint_as_float(A.y & 0xffff0000u);
            acc[4] += __uint_as_float(B.x << 16);
            acc[5] += __uint_as_float(B.x & 0xffff0000u);
            acc[6] += __uint_as_float(B.y << 16);
            acc[7] += __uint_as_float(B.y & 0xffff0000u);
        } else if constexpr (MODE == 1) {
            const unsigned short* xp = (const unsigned short*)xrv + (size_t)(b * 96 + c) * HW + h * 256 + wbase;
            uint4 u = *(const uint4*)xp;
            acc[0] += __uint_as_float(u.x << 16);
            acc[1] += __uint_as_float(u.x & 0xffff0000u);
            acc[2] += __uint_as_float(u.y << 16);
            acc[3] += __uint_as_float(u.y & 0xffff0000u);
            acc[4] += __uint_as_float(u.z << 16);
            acc[5] += __uint_as_float(u.z & 0xffff0000u);
            acc[6] += __uint_as_float(u.w << 16);
            acc[7] += __uint_as_float(u.w & 0xffff0000u);
        } else {
            const float* xp = (const float*)xrv + (size_t)(b * 96 + c) * HW + h * 256;
            f32x4 x0 = *(const f32x4*)(xp + wbase);
            f32x4 x1 = *(const f32x4*)(xp + wbase + 4);
#pragma unroll
            for (int i = 0; i < 4; ++i) { acc[i] += x0[i]; acc[4 + i] += x1[i]; }
        }
#pragma unroll
        for (int i = 0; i < 8; ++i) Ts[(g * 8 + i) * 104 + c] = (__bf16)acc[i];
    }
    __syncthreads();
    int lane = tid & 63;
    int l16 = lane & 15;
    int g8 = (lane >> 4) << 3;
    int g4 = (lane >> 4) << 2;
    int wv = tid >> 6;   // 8 waves -> 16 px rows each
    f32x4 po[6];
#pragma unroll
    for (int ni = 0; ni < 6; ++ni) po[ni] = (f32x4){0.f, 0.f, 0.f, 0.f};
#pragma unroll
    for (int ks = 0; ks < 3; ++ks) {
        bf16x8 Av = *(const bf16x8*)(Ts + (wv * 16 + l16) * 104 + ks * 32 + g8);
#pragma unroll
        for (int ni = 0; ni < 6; ++ni) {
            int o = ni * 16 + l16;
            bf16x8 Bh = *(const bf16x8*)(WpHi + o * 96 + ks * 32 + g8);
            bf16x8 Bl = *(const bf16x8*)(WpLo + o * 96 + ks * 32 + g8);
            po[ni] = __builtin_amdgcn_mfma_f32_16x16x32_bf16(Av, Bh, po[ni], 0, 0, 0);
            po[ni] = __builtin_amdgcn_mfma_f32_16x16x32_bf16(Av, Bl, po[ni], 0, 0, 0);
        }
    }
#pragma unroll
    for (int ni = 0; ni < 6; ++ni) {
        int o = ni * 16 + l16;
        float bias = pb[o];
        f32x4 v = po[ni];
        v[0] += bias; v[1] += bias; v[2] += bias; v[3] += bias;
        *(f32x4*)(T + (size_t)(b * 96 + o) * HW + h * 256 + w0 + wv * 16 + g4) = v;
    }
}

extern "C" void kernel_launch(void* const* d_in, const int* in_sizes, int n_in,
                              void* d_out, int out_size, void* d_ws, size_t ws_size,
                              hipStream_t stream) {
    const float* x      = (const float*)d_in[0];
    const float* V_w    = (const float*)d_in[1];
    const float* V_b    = (const float*)d_in[2];
    const float* QK_w   = (const float*)d_in[3];
    const float* QK_b   = (const float*)d_in[4];
    const float* proj_w = (const float*)d_in[5];
    const float* proj_b = (const float*)d_in[6];
    const float* dw_w   = (const float*)d_in[7];
    const float* dw_b   = (const float*)d_in[8];
    const float* mw1    = (const float*)d_in[9];
    const float* mb1    = (const float*)d_in[10];
    const float* mw2    = (const float*)d_in[11];
    const float* mb2    = (const float*)d_in[12];
    float* out = (float*)d_out;

    char* ws = (char*)d_ws;
    const size_t VB = 100663296;   // 8*96*65536*2
    const size_t TAB = 49152 + 2 * 55296 + 2 * 18432;
    int mode = (ws_size >= 3 * VB + TAB) ? 2 : (ws_size >= 2 * VB + TAB) ? 1 : 0;

    __hip_bfloat16* Vbuf = (__hip_bfloat16*)ws;
    size_t off = VB;
    unsigned short* xr16 = nullptr;
    __bf16* xT = nullptr;
    if (mode >= 1) { xr16 = (unsigned short*)(ws + off); off += VB; }
    if (mode == 2) { xT = (__bf16*)(ws + off); off += VB; }
    float*  biasF = (float*)(ws + off); off += 49152;
    __bf16* Whi   = (__bf16*)(ws + off); off += 55296;
    __bf16* Wlo   = (__bf16*)(ws + off); off += 55296;
    __bf16* WpHi  = (__bf16*)(ws + off); off += 18432;
    __bf16* WpLo  = (__bf16*)(ws + off);

    bias_kernel<<<48, 256, 0, stream>>>(mw1, mb1, mw2, mb2, biasF);
    wtrans_kernel<<<144, 256, 0, stream>>>(QK_w, V_w, proj_w, Whi, Wlo, WpHi, WpLo);
    if (mode == 2) {
        xprep_kernel<<<2048, 256, 0, stream>>>(x, xT);
        fused_qkv_attn<2><<<2048, 256, 0, stream>>>(x, xT, Whi, Wlo, QK_b, V_b, biasF,
                                                    (unsigned short*)Vbuf, (void*)xr16);
        dwproj_kernel<2><<<4096, 512, 0, stream>>>(Vbuf, dw_w, dw_b, WpHi, WpLo, proj_b,
                                                   (const void*)xr16, out);
    } else if (mode == 1) {
        fused_qkv_attn<1><<<2048, 256, 0, stream>>>(x, nullptr, Whi, Wlo, QK_b, V_b, biasF,
                                                    (unsigned short*)Vbuf, (void*)xr16);
        dwproj_kernel<1><<<4096, 512, 0, stream>>>(Vbuf, dw_w, dw_b, WpHi, WpLo, proj_b,
                                                   (const void*)xr16, out);
    } else {
        fused_qkv_attn<0><<<2048, 256, 0, stream>>>(x, nullptr, Whi, Wlo, QK_b, V_b, biasF,
                                                    (unsigned short*)Vbuf, (void*)out);
        dwproj_kernel<0><<<4096, 512, 0, stream>>>(Vbuf, dw_w, dw_b, WpHi, WpLo, proj_b,
                                                   (const void*)out, out);
    }
}

// Round 17
// 645.191 us; speedup vs baseline: 1.1300x; 1.1300x over previous
//
#include <hip/hip_runtime.h>
#include <hip/hip_bf16.h>

#define HW 65536
#define SCALE_Q 0.17677669529663687f

typedef __bf16 bf16x8 __attribute__((ext_vector_type(8)));
typedef float f32x4 __attribute__((ext_vector_type(4)));

// ---------------- K0: rel-pos MLP bias in C-fragment layout ----------------
__global__ void bias_kernel(const float* __restrict__ w1, const float* __restrict__ b1,
                            const float* __restrict__ w2, const float* __restrict__ b2,
                            float* __restrict__ biasF) {
    int gid = blockIdx.x * blockDim.x + threadIdx.x;
    if (gid >= 12288) return;
    int lane = gid & 63, r = (gid >> 6) & 3, ni = (gid >> 8) & 3, mi = (gid >> 10) & 3, h = gid >> 12;
    int i = mi * 16 + ((lane >> 4) << 2) + r;
    int j = ni * 16 + (lane & 15);
    float di = (float)((i >> 3) - (j >> 3));
    float dj = (float)((i & 7) - (j & 7));
    float r0 = (di > 0.f ? 1.f : (di < 0.f ? -1.f : 0.f)) * log1pf(fabsf(di));
    float r1 = (dj > 0.f ? 1.f : (dj < 0.f ? -1.f : 0.f)) * log1pf(fabsf(dj));
    float acc = 0.f;
    for (int t = 0; t < 256; ++t) {
        float u = fmaf(w1[2 * t], r0, fmaf(w1[2 * t + 1], r1, b1[t]));
        u = fmaxf(u, 0.f);
        acc = fmaf(w2[h * 256 + t], u, acc);
    }
    biasF[gid] = acc + b2[h];
}

// ---------------- K0b: weight prep (bf16 hi/lo: QKV rows + proj rows) ----------
__global__ void wtrans_kernel(const float* __restrict__ QK_w, const float* __restrict__ V_w,
                              const float* __restrict__ proj_w,
                              __bf16* __restrict__ Whi, __bf16* __restrict__ Wlo,
                              __bf16* __restrict__ WpHi, __bf16* __restrict__ WpLo) {
    int idx = blockIdx.x * blockDim.x + threadIdx.x;
    if (idx < 288 * 96) {
        int oo = idx / 96, c = idx - oo * 96;
        int h = oo / 96, rem = oo - h * 96, grp = rem >> 5, d = rem & 31;
        float w = (grp == 0) ? QK_w[(h * 32 + d) * 96 + c]
                : (grp == 1) ? QK_w[(96 + h * 32 + d) * 96 + c]
                             : V_w[(h * 32 + d) * 96 + c];
        __bf16 hi = (__bf16)w;
        Whi[idx] = hi;
        Wlo[idx] = (__bf16)(w - (float)hi);
    } else if (idx < 288 * 96 + 96 * 96) {
        int rdx = idx - 288 * 96;
        float w = proj_w[rdx];
        __bf16 hi = (__bf16)w;
        WpHi[rdx] = hi;
        WpLo[rdx] = (__bf16)(w - (float)hi);
    }
}

// ---------------- K1: fused QKV conv + window attention (barrier-free, r14 base) ------
// MODE 1: xr window-tiled bf16 [plane][1024 win][64 tok] (wave-owned 128B lines).
// MODE 0: xr f32 planar (d_out).
template <int MODE>
__global__ __launch_bounds__(256, 4) void fused_qkv_attn(
    const float* __restrict__ x,
    const __bf16* __restrict__ Whi, const __bf16* __restrict__ Wlo,
    const float* __restrict__ QK_b, const float* __restrict__ V_b,
    const float* __restrict__ biasF,
    unsigned short* __restrict__ Vout, void* __restrict__ xrv) {
    __shared__ __align__(16) char lds[39936];
    int tid = threadIdx.x;
    int w4 = tid >> 6;
    int lane = tid & 63;
    int l16 = lane & 15;
    int g8 = (lane >> 4) << 3;
    int g4 = (lane >> 4) << 2;
    int bx0 = blockIdx.x;
    int bxs = (bx0 & 7) * 256 + (bx0 >> 3);
    int b = bxs >> 8;
    int wh = (bxs >> 3) & 31;
    int ww0 = (bxs & 7) << 2;
    int wh8 = wh << 3;
    int ww = ww0 + w4;
    int wl = wh * 32 + ww;
    int ti = lane >> 3, tj = lane & 7;
    int ph = (wh8 + ti + 4) & 255;
    int pw = ((ww << 3) + tj + 4) & 255;
    int pos   = ph * 256 + pw;
    int pos_s = (wh8 + ti) * 256 + (ww << 3) + tj;

    // A-fragments directly from global (remat-tolerant; L3 absorbs re-reads)
    const float* xb = x + (size_t)b * 96 * HW;
    bf16x8 Ah[4][3];
#pragma unroll
    for (int mi = 0; mi < 4; ++mi) {
        int t = mi * 16 + l16;
        int py = (wh8 + (t >> 3) + 4) & 255;
        int px = ((ww << 3) + (t & 7) + 4) & 255;
        const float* xp = xb + py * 256 + px + (size_t)g8 * HW;
#pragma unroll
        for (int ks = 0; ks < 3; ++ks)
#pragma unroll
            for (int e = 0; e < 8; ++e)
                Ah[mi][ks][e] = (__bf16)xp[(size_t)(ks * 32 + e) * HW];
    }

    char* hb = lds + w4 * 9984;
    __bf16* slab = (__bf16*)hb;            // [64][40] bf16: Q, K, P stages; Xrt overlay
    __bf16* Vt   = (__bf16*)(hb + 5120);   // [32 d][72 tok]
    float*  Xr   = (float*)hb;             // [64][36] f32 overlay (MODE 0 epilogue)

    bool bhh = (wh == 31), bww = (ww == 31);
    int rc[4];
#pragma unroll
    for (int ni = 0; ni < 4; ++ni) {
        int t = ni * 16 + l16;
        rc[ni] = (bhh ? (((t >> 3) < 4) ? 1 : 2) : 0) * 3 + (bww ? (((t & 7) < 4) ? 1 : 2) : 0);
    }

#pragma unroll 1
    for (int h = 0; h < 3; ++h) {
        bf16x8 Qf[4], Kf[4];
        // ---- Q (1-pass) ----
        {
            f32x4 acc[4][2];
#pragma unroll
            for (int mi = 0; mi < 4; ++mi)
#pragma unroll
                for (int ni = 0; ni < 2; ++ni) acc[mi][ni] = (f32x4){0.f, 0.f, 0.f, 0.f};
            __builtin_amdgcn_s_setprio(1);
#pragma unroll
            for (int ks = 0; ks < 3; ++ks)
#pragma unroll
                for (int ni = 0; ni < 2; ++ni) {
                    bf16x8 Bh = *(const bf16x8*)(Whi + (h * 96 + ni * 16 + l16) * 96 + ks * 32 + g8);
#pragma unroll
                    for (int mi = 0; mi < 4; ++mi)
                        acc[mi][ni] = __builtin_amdgcn_mfma_f32_16x16x32_bf16(Ah[mi][ks], Bh, acc[mi][ni], 0, 0, 0);
                }
            __builtin_amdgcn_s_setprio(0);
#pragma unroll
            for (int ni = 0; ni < 2; ++ni) {
                float bias = QK_b[h * 32 + ni * 16 + l16];
#pragma unroll
                for (int mi = 0; mi < 4; ++mi)
#pragma unroll
                    for (int r = 0; r < 4; ++r)
                        slab[(mi * 16 + g4 + r) * 40 + ni * 16 + l16] = (__bf16)((acc[mi][ni][r] + bias) * SCALE_Q);
            }
#pragma unroll
            for (int mi = 0; mi < 4; ++mi) Qf[mi] = *(const bf16x8*)(slab + (mi * 16 + l16) * 40 + g8);
        }
        // ---- K (1-pass) ----
        {
            f32x4 acc[4][2];
#pragma unroll
            for (int mi = 0; mi < 4; ++mi)
#pragma unroll
                for (int ni = 0; ni < 2; ++ni) acc[mi][ni] = (f32x4){0.f, 0.f, 0.f, 0.f};
            __builtin_amdgcn_s_setprio(1);
#pragma unroll
            for (int ks = 0; ks < 3; ++ks)
#pragma unroll
                for (int ni = 0; ni < 2; ++ni) {
                    bf16x8 Bh = *(const bf16x8*)(Whi + (h * 96 + 32 + ni * 16 + l16) * 96 + ks * 32 + g8);
#pragma unroll
                    for (int mi = 0; mi < 4; ++mi)
                        acc[mi][ni] = __builtin_amdgcn_mfma_f32_16x16x32_bf16(Ah[mi][ks], Bh, acc[mi][ni], 0, 0, 0);
                }
            __builtin_amdgcn_s_setprio(0);
#pragma unroll
            for (int ni = 0; ni < 2; ++ni) {
                float bias = QK_b[96 + h * 32 + ni * 16 + l16];
#pragma unroll
                for (int mi = 0; mi < 4; ++mi)
#pragma unroll
                    for (int r = 0; r < 4; ++r)
                        slab[(mi * 16 + g4 + r) * 40 + ni * 16 + l16] = (__bf16)(acc[mi][ni][r] + bias);
            }
#pragma unroll
            for (int mi = 0; mi < 4; ++mi) Kf[mi] = *(const bf16x8*)(slab + (mi * 16 + l16) * 40 + g8);
        }
        // ---- V (1-pass) ----
        {
            f32x4 acc[4][2];
#pragma unroll
            for (int mi = 0; mi < 4; ++mi)
#pragma unroll
                for (int ni = 0; ni < 2; ++ni) acc[mi][ni] = (f32x4){0.f, 0.f, 0.f, 0.f};
            __builtin_amdgcn_s_setprio(1);
#pragma unroll
            for (int ks = 0; ks < 3; ++ks)
#pragma unroll
                for (int ni = 0; ni < 2; ++ni) {
                    bf16x8 Bh = *(const bf16x8*)(Whi + (h * 96 + 64 + ni * 16 + l16) * 96 + ks * 32 + g8);
#pragma unroll
                    for (int mi = 0; mi < 4; ++mi)
                        acc[mi][ni] = __builtin_amdgcn_mfma_f32_16x16x32_bf16(Ah[mi][ks], Bh, acc[mi][ni], 0, 0, 0);
                }
            __builtin_amdgcn_s_setprio(0);
#pragma unroll
            for (int ni = 0; ni < 2; ++ni) {
                float bias = V_b[h * 32 + ni * 16 + l16];
#pragma unroll
                for (int mi = 0; mi < 4; ++mi)
#pragma unroll
                    for (int r = 0; r < 4; ++r)
                        Vt[(ni * 16 + l16) * 72 + mi * 16 + g4 + r] = (__bf16)(acc[mi][ni][r] + bias);
            }
        }
#pragma unroll
        for (int d = 0; d < 32; ++d)
            Vout[(size_t)(b * 96 + h * 32 + d) * HW + pos_s] = ((const unsigned short*)Vt)[d * 72 + lane];

        // ---- QK^T ----
        f32x4 sc[4][4];
        __builtin_amdgcn_s_setprio(1);
#pragma unroll
        for (int mi = 0; mi < 4; ++mi)
#pragma unroll
            for (int ni = 0; ni < 4; ++ni) {
                sc[mi][ni] = (f32x4){0.f, 0.f, 0.f, 0.f};
                sc[mi][ni] = __builtin_amdgcn_mfma_f32_16x16x32_bf16(Qf[mi], Kf[ni], sc[mi][ni], 0, 0, 0);
            }
        __builtin_amdgcn_s_setprio(0);
        const float* bF = biasF + h * 4096;
#pragma unroll
        for (int mi = 0; mi < 4; ++mi)
#pragma unroll
            for (int r = 0; r < 4; ++r) {
                int row = mi * 16 + g4 + r;
                float s0 = sc[mi][0][r] + bF[((mi * 4 + 0) * 4 + r) * 64 + lane];
                float s1 = sc[mi][1][r] + bF[((mi * 4 + 1) * 4 + r) * 64 + lane];
                float s2 = sc[mi][2][r] + bF[((mi * 4 + 2) * 4 + r) * 64 + lane];
                float s3 = sc[mi][3][r] + bF[((mi * 4 + 3) * 4 + r) * 64 + lane];
                if (bhh || bww) {
                    int rr = (bhh ? (((row >> 3) < 4) ? 1 : 2) : 0) * 3 +
                             (bww ? (((row & 7) < 4) ? 1 : 2) : 0);
                    if (rr != rc[0]) s0 -= 100.f;
                    if (rr != rc[1]) s1 -= 100.f;
                    if (rr != rc[2]) s2 -= 100.f;
                    if (rr != rc[3]) s3 -= 100.f;
                }
                float mm = fmaxf(fmaxf(s0, s1), fmaxf(s2, s3));
                mm = fmaxf(mm, __shfl_xor(mm, 1));
                mm = fmaxf(mm, __shfl_xor(mm, 2));
                mm = fmaxf(mm, __shfl_xor(mm, 4));
                mm = fmaxf(mm, __shfl_xor(mm, 8));
                float e0 = __expf(s0 - mm), e1 = __expf(s1 - mm);
                float e2 = __expf(s2 - mm), e3 = __expf(s3 - mm);
                float sum = e0 + e1 + e2 + e3;
                sum += __shfl_xor(sum, 1);
                sum += __shfl_xor(sum, 2);
                sum += __shfl_xor(sum, 4);
                sum += __shfl_xor(sum, 8);
                float inv = 1.f / sum;
                sc[mi][0][r] = e0 * inv;
                sc[mi][1][r] = e1 * inv;
                sc[mi][2][r] = e2 * inv;
                sc[mi][3][r] = e3 * inv;
            }
        // ---- PV (P staged through slab) ----
        f32x4 po[4][2];
#pragma unroll
        for (int mi = 0; mi < 4; ++mi)
#pragma unroll
            for (int ni = 0; ni < 2; ++ni) po[mi][ni] = (f32x4){0.f, 0.f, 0.f, 0.f};
#pragma unroll
        for (int ks = 0; ks < 2; ++ks) {
#pragma unroll
            for (int mi = 0; mi < 4; ++mi)
#pragma unroll
                for (int r = 0; r < 4; ++r) {
                    int row = mi * 16 + g4 + r;
                    slab[row * 40 + l16]      = (__bf16)sc[mi][ks * 2 + 0][r];
                    slab[row * 40 + 16 + l16] = (__bf16)sc[mi][ks * 2 + 1][r];
                }
            bf16x8 Vf[2], Pf;
#pragma unroll
            for (int ni = 0; ni < 2; ++ni)
                Vf[ni] = *(const bf16x8*)(Vt + (ni * 16 + l16) * 72 + ks * 32 + g8);
            __builtin_amdgcn_s_setprio(1);
#pragma unroll
            for (int mi = 0; mi < 4; ++mi) {
                Pf = *(const bf16x8*)(slab + (mi * 16 + l16) * 40 + g8);
#pragma unroll
                for (int ni = 0; ni < 2; ++ni)
                    po[mi][ni] = __builtin_amdgcn_mfma_f32_16x16x32_bf16(Pf, Vf[ni], po[mi][ni], 0, 0, 0);
            }
            __builtin_amdgcn_s_setprio(0);
        }
        // ---- xr epilogue ----
        if constexpr (MODE == 1) {
            // within-wave transpose to Xrt [32 d][stride 72] bf16, then wave-owned 128B lines
            __bf16* Xrt = slab;
#pragma unroll
            for (int mi = 0; mi < 4; ++mi)
#pragma unroll
                for (int ni = 0; ni < 2; ++ni)
#pragma unroll
                    for (int r = 0; r < 4; ++r)
                        Xrt[(ni * 16 + l16) * 72 + mi * 16 + g4 + r] = (__bf16)po[mi][ni][r];
            int d = lane >> 1, half = lane & 1;
            const unsigned short* src = (const unsigned short*)Xrt + d * 72 + half * 32;
            unsigned short* dst = (unsigned short*)xrv +
                ((size_t)(b * 96 + h * 32 + d) * 1024 + wl) * 64 + half * 32;
#pragma unroll
            for (int i = 0; i < 4; ++i)
                *(uint4*)(dst + i * 8) = *(const uint4*)(src + i * 8);
        } else {
#pragma unroll
            for (int mi = 0; mi < 4; ++mi)
#pragma unroll
                for (int ni = 0; ni < 2; ++ni)
#pragma unroll
                    for (int r = 0; r < 4; ++r)
                        Xr[(mi * 16 + g4 + r) * 36 + ni * 16 + l16] = po[mi][ni][r];
            float* xrg = (float*)xrv + (size_t)(b * 96 + h * 32) * HW + pos;
#pragma unroll
            for (int c4 = 0; c4 < 8; ++c4) {
                f32x4 v = *(const f32x4*)(Xr + lane * 36 + c4 * 4);
                xrg[(size_t)(c4 * 4 + 0) * HW] = v[0];
                xrg[(size_t)(c4 * 4 + 1) * HW] = v[1];
                xrg[(size_t)(c4 * 4 + 2) * HW] = v[2];
                xrg[(size_t)(c4 * 4 + 3) * HW] = v[3];
            }
        }
    }
}

// ---------------- K2: dwconv + xr -> swizzled bf16 LDS, 2-pass MFMA proj ----
// Ts XOR-swizzle: byte ^= ((px>>3)&7)<<4 — kills the 16-way g-lane write conflict
// (g-stride 1664 B ≡ 0 mod 128 -> same bank without it). 16B-align preserved.
template <int MODE>
__global__ __launch_bounds__(256) void dwproj_kernel(
    const __hip_bfloat16* __restrict__ Vs, const float* __restrict__ dw_w,
    const float* __restrict__ dw_b, const __bf16* __restrict__ WpHi,
    const __bf16* __restrict__ WpLo, const float* __restrict__ pb,
    const void* __restrict__ xrv, float* __restrict__ T) {
    __shared__ __align__(16) __bf16 Ts[13312];   // [128 px][104] bf16, swizzled
    char* Tsb = (char*)Ts;
    int bx0 = blockIdx.x;
    int bx = (bx0 & 7) * 512 + (bx0 >> 3);   // XCD-contiguous rows (4096 % 8 == 0)
    int half = bx & 1, h = (bx >> 1) & 255, b = bx >> 9;
    int w0 = half << 7;
    int tid = threadIdx.x;
    for (int task = tid; task < 1536; task += 256) {
        int c = task >> 4, g = task & 15;
        int wbase = w0 + (g << 3);
        const __hip_bfloat16* Vp = Vs + (size_t)(b * 96 + c) * HW;
        const float* wt = dw_w + c * 25;
        float acc[8];
        float bias = dw_b[c];
#pragma unroll
        for (int i = 0; i < 8; ++i) acc[i] = bias;
        bool fast = (wbase >= 8) && (wbase <= 240);
#pragma unroll
        for (int dy = -2; dy <= 2; ++dy) {
            int hh = h + dy;
            hh = hh < 0 ? -hh : (hh > 255 ? 510 - hh : hh);
            int hs = (hh + 252) & 255;
            const __hip_bfloat16* row = Vp + hs * 256;
            float xv[12];
            if (fast) {
                const uint* rp = (const uint*)(row + (wbase - 6));
#pragma unroll
                for (int g2 = 0; g2 < 6; ++g2) {
                    uint u = rp[g2];
                    xv[2 * g2]     = __uint_as_float(u << 16);
                    xv[2 * g2 + 1] = __uint_as_float(u & 0xffff0000u);
                }
            } else {
#pragma unroll
                for (int idx = 0; idx < 12; ++idx) {
                    int cw = wbase - 2 + idx;
                    cw = cw < 0 ? -cw : (cw > 255 ? 510 - cw : cw);
                    int cs = (cw + 252) & 255;
                    uint u = *(const unsigned short*)(row + cs);
                    xv[idx] = __uint_as_float(u << 16);
                }
            }
            const float* w5 = wt + (dy + 2) * 5;
#pragma unroll
            for (int dx = 0; dx < 5; ++dx) {
                float wv = w5[dx];
#pragma unroll
                for (int i = 0; i < 8; ++i) acc[i] = fmaf(wv, xv[i + dx], acc[i]);
            }
        }
        if constexpr (MODE == 1) {
            // xr window-tiled in SHIFTED space (validated r16): cols [wbase,wbase+8) =
            // tokens 4..7 of window (ps2>>3) then tokens 0..3 of window (wbase>>3).
            int hs2 = (h + 252) & 255;
            int ps2 = (wbase + 252) & 255;
            int wrow = (hs2 >> 3) * 32;
            int rowoff = (hs2 & 7) * 8;
            const unsigned short* base = (const unsigned short*)xrv + (size_t)(b * 96 + c) * HW;
            uint2 A = *(const uint2*)(base + (size_t)(wrow + (ps2 >> 3)) * 64 + rowoff + 4);
            uint2 B = *(const uint2*)(base + (size_t)(wrow + (wbase >> 3)) * 64 + rowoff);
            acc[0] += __uint_as_float(A.x << 16);
            acc[1] += __uint_as_float(A.x & 0xffff0000u);
            acc[2] += __uint_as_float(A.y << 16);
            acc[3] += __uint_as_float(A.y & 0xffff0000u);
            acc[4] += __uint_as_float(B.x << 16);
            acc[5] += __uint_as_float(B.x & 0xffff0000u);
            acc[6] += __uint_as_float(B.y << 16);
            acc[7] += __uint_as_float(B.y & 0xffff0000u);
        } else {
            const float* xp = (const float*)xrv + (size_t)(b * 96 + c) * HW + h * 256;
            f32x4 x0 = *(const f32x4*)(xp + wbase);
            f32x4 x1 = *(const f32x4*)(xp + wbase + 4);
#pragma unroll
            for (int i = 0; i < 4; ++i) { acc[i] += x0[i]; acc[4 + i] += x1[i]; }
        }
#pragma unroll
        for (int i = 0; i < 8; ++i) {
            int px = g * 8 + i;
            *(__bf16*)(Tsb + (((px * 104 + c) * 2) ^ ((g & 7) << 4))) = (__bf16)acc[i];
        }
    }
    __syncthreads();
    int lane = tid & 63;
    int l16 = lane & 15;
    int g8 = (lane >> 4) << 3;
    int g4 = (lane >> 4) << 2;
    int wv = tid >> 6;
    f32x4 po[2][6];
#pragma unroll
    for (int mi = 0; mi < 2; ++mi)
#pragma unroll
        for (int ni = 0; ni < 6; ++ni) po[mi][ni] = (f32x4){0.f, 0.f, 0.f, 0.f};
#pragma unroll
    for (int ks = 0; ks < 3; ++ks) {
        bf16x8 Av[2];
#pragma unroll
        for (int mi = 0; mi < 2; ++mi) {
            int px = wv * 32 + mi * 16 + l16;
            Av[mi] = *(const bf16x8*)(Tsb + (((px * 104 + ks * 32 + g8) * 2) ^ (((px >> 3) & 7) << 4)));
        }
#pragma unroll
        for (int ni = 0; ni < 6; ++ni) {
            int o = ni * 16 + l16;
            bf16x8 Bh = *(const bf16x8*)(WpHi + o * 96 + ks * 32 + g8);
            bf16x8 Bl = *(const bf16x8*)(WpLo + o * 96 + ks * 32 + g8);
#pragma unroll
            for (int mi = 0; mi < 2; ++mi) {
                po[mi][ni] = __builtin_amdgcn_mfma_f32_16x16x32_bf16(Av[mi], Bh, po[mi][ni], 0, 0, 0);
                po[mi][ni] = __builtin_amdgcn_mfma_f32_16x16x32_bf16(Av[mi], Bl, po[mi][ni], 0, 0, 0);
            }
        }
    }
#pragma unroll
    for (int ni = 0; ni < 6; ++ni) {
        int o = ni * 16 + l16;
        float bias = pb[o];
#pragma unroll
        for (int mi = 0; mi < 2; ++mi) {
            f32x4 v = po[mi][ni];
            v[0] += bias; v[1] += bias; v[2] += bias; v[3] += bias;
            *(f32x4*)(T + (size_t)(b * 96 + o) * HW + h * 256 + w0 + wv * 32 + mi * 16 + g4) = v;
        }
    }
}

extern "C" void kernel_launch(void* const* d_in, const int* in_sizes, int n_in,
                              void* d_out, int out_size, void* d_ws, size_t ws_size,
                              hipStream_t stream) {
    const float* x      = (const float*)d_in[0];
    const float* V_w    = (const float*)d_in[1];
    const float* V_b    = (const float*)d_in[2];
    const float* QK_w   = (const float*)d_in[3];
    const float* QK_b   = (const float*)d_in[4];
    const float* proj_w = (const float*)d_in[5];
    const float* proj_b = (const float*)d_in[6];
    const float* dw_w   = (const float*)d_in[7];
    const float* dw_b   = (const float*)d_in[8];
    const float* mw1    = (const float*)d_in[9];
    const float* mb1    = (const float*)d_in[10];
    const float* mw2    = (const float*)d_in[11];
    const float* mb2    = (const float*)d_in[12];
    float* out = (float*)d_out;

    char* ws = (char*)d_ws;
    const size_t VB = 100663296;   // 8*96*65536*2
    const size_t TAB = 49152 + 2 * 55296 + 2 * 18432;
    int mode = (ws_size >= 2 * VB + TAB) ? 1 : 0;

    __hip_bfloat16* Vbuf = (__hip_bfloat16*)ws;
    size_t off = VB;
    unsigned short* xr16 = nullptr;
    if (mode == 1) { xr16 = (unsigned short*)(ws + off); off += VB; }
    float*  biasF = (float*)(ws + off); off += 49152;
    __bf16* Whi   = (__bf16*)(ws + off); off += 55296;
    __bf16* Wlo   = (__bf16*)(ws + off); off += 55296;
    __bf16* WpHi  = (__bf16*)(ws + off); off += 18432;
    __bf16* WpLo  = (__bf16*)(ws + off);

    bias_kernel<<<48, 256, 0, stream>>>(mw1, mb1, mw2, mb2, biasF);
    wtrans_kernel<<<144, 256, 0, stream>>>(QK_w, V_w, proj_w, Whi, Wlo, WpHi, WpLo);
    if (mode == 1) {
        fused_qkv_attn<1><<<2048, 256, 0, stream>>>(x, Whi, Wlo, QK_b, V_b, biasF,
                                                    (unsigned short*)Vbuf, (void*)xr16);
        dwproj_kernel<1><<<4096, 256, 0, stream>>>(Vbuf, dw_w, dw_b, WpHi, WpLo, proj_b,
                                                   (const void*)xr16, out);
    } else {
        fused_qkv_attn<0><<<2048, 256, 0, stream>>>(x, Whi, Wlo, QK_b, V_b, biasF,
                                                    (unsigned short*)Vbuf, (void*)out);
        dwproj_kernel<0><<<4096, 256, 0, stream>>>(Vbuf, dw_w, dw_b, WpHi, WpLo, proj_b,
                                                   (const void*)out, out);
    }
}